// Round 1
// baseline (664.513 us; speedup 1.0000x reference)
//
#include <hip/hip_runtime.h>

// Problem constants: BS=32, SEQ=2048, IN=512, H=256, L=2
#define SEQL 2048
#define BSZ  32
#define HDIM 256
#define MTOT (BSZ*SEQL)          // 65536 rows
#define XXN  ((size_t)MTOT*512)  // xx output elems

typedef short v8s __attribute__((ext_vector_type(8)));
typedef float v4f __attribute__((ext_vector_type(4)));

__device__ __forceinline__ short f2bf(float f) {
  unsigned u = __builtin_bit_cast(unsigned, f);
  u = u + 0x7FFFu + ((u >> 16) & 1u);   // RNE
  return (short)(u >> 16);
}

// C[m][n] = act( sum_k A[m][k]*W[n][k] + bias[n] ), A row stride sa, W is [256][K],
// C row stride 256. act: 0=none, 1=sigmoid. Tile 128x128, 4 waves of 64x64, bf16 MFMA.
__global__ __launch_bounds__(256) void gemm_bias_act(
    const float* __restrict__ A, int sa,
    const float* __restrict__ W, int K,
    const float* __restrict__ bias,
    float* __restrict__ C, int act)
{
  __shared__ v8s As8[128*5];   // [128 rows][32 k + 8 pad] shorts
  __shared__ v8s Bs8[128*5];
  short* As = (short*)As8;
  short* Bs = (short*)Bs8;

  int tid  = threadIdx.x;
  int m0   = blockIdx.x * 128;
  int n0   = blockIdx.y * 128;
  int lane = tid & 63;
  int wid  = tid >> 6;
  int wr   = wid >> 1, wc = wid & 1;
  int quad = lane >> 4, r16 = lane & 15;

  int srow = tid >> 1;          // staging row 0..127
  int sseg = (tid & 1) * 16;    // k segment 0 or 16

  v4f acc[4][4];
  #pragma unroll
  for (int i = 0; i < 4; ++i)
    #pragma unroll
    for (int j = 0; j < 4; ++j)
      acc[i][j] = (v4f){0.f, 0.f, 0.f, 0.f};

  const float* aBase = A + (long)(m0 + srow)*sa + sseg;
  const float* wBase = W + (long)(n0 + srow)*K + sseg;

  for (int kk = 0; kk < K; kk += 32) {
    __syncthreads();
    float av[16], wv[16];
    const float4* ap = (const float4*)(aBase + kk);
    const float4* wp = (const float4*)(wBase + kk);
    #pragma unroll
    for (int u = 0; u < 4; ++u) {
      float4 t = ap[u];
      av[u*4+0]=t.x; av[u*4+1]=t.y; av[u*4+2]=t.z; av[u*4+3]=t.w;
      float4 s = wp[u];
      wv[u*4+0]=s.x; wv[u*4+1]=s.y; wv[u*4+2]=s.z; wv[u*4+3]=s.w;
    }
    v8s pa0, pa1, pw0, pw1;
    #pragma unroll
    for (int u = 0; u < 8; ++u) {
      pa0[u] = f2bf(av[u]);   pa1[u] = f2bf(av[8+u]);
      pw0[u] = f2bf(wv[u]);   pw1[u] = f2bf(wv[8+u]);
    }
    *(v8s*)&As[srow*40 + sseg]     = pa0;
    *(v8s*)&As[srow*40 + sseg + 8] = pa1;
    *(v8s*)&Bs[srow*40 + sseg]     = pw0;
    *(v8s*)&Bs[srow*40 + sseg + 8] = pw1;
    __syncthreads();

    // A-frag: A[m=lane&15][k=quad*8+j]; B-frag: B[k=quad*8+j][n=lane&15] = W[n][k]
    v8s af[4], bfv[4];
    #pragma unroll
    for (int i = 0; i < 4; ++i)
      af[i] = *(const v8s*)&As[(wr*64 + i*16 + r16)*40 + quad*8];
    #pragma unroll
    for (int j = 0; j < 4; ++j)
      bfv[j] = *(const v8s*)&Bs[(wc*64 + j*16 + r16)*40 + quad*8];
    #pragma unroll
    for (int i = 0; i < 4; ++i)
      #pragma unroll
      for (int j = 0; j < 4; ++j)
        acc[i][j] = __builtin_amdgcn_mfma_f32_16x16x32_bf16(af[i], bfv[j], acc[i][j], 0, 0, 0);
  }

  // Epilogue: C/D layout col=lane&15, row=quad*4+reg
  #pragma unroll
  for (int j = 0; j < 4; ++j) {
    int col = n0 + wc*64 + j*16 + r16;
    float bv = bias[col];
    #pragma unroll
    for (int i = 0; i < 4; ++i) {
      int rowb = m0 + wr*64 + i*16 + quad*4;
      #pragma unroll
      for (int r = 0; r < 4; ++r) {
        float v = acc[i][j][r] + bv;
        if (act) {
          float e = __builtin_amdgcn_exp2f(v * -1.4426950408889634f);
          v = __builtin_amdgcn_rcpf(1.f + e);
        }
        C[(long)(rowb + r)*HDIM + col] = v;
      }
    }
  }
}

// One independent chain per (dir, batch, feature): h = tanh(x*(g*h + (1-g)*x)).
// 256 blocks x 64 threads: blk = d*128 + b*4 + fg. Chunked register double-buffer.
// Y is d_out xx region [b][t][512]; ltr writes feat f, rtl writes 256+f at flipped t.
__global__ __launch_bounds__(64) void recur(
    const float* __restrict__ X, int sx, int xoffR,
    const float* __restrict__ Gl, const float* __restrict__ Gr,
    float* __restrict__ Y, float* __restrict__ hout)
{
  const int T = 16;
  const int NC = SEQL / T;
  int blk = blockIdx.x;
  int fg = blk & 3;
  int b  = (blk >> 2) & 31;
  int d  = blk >> 7;
  int f  = fg*64 + threadIdx.x;
  int t0  = d ? (SEQL-1) : 0;
  int stp = d ? -1 : 1;
  const float* G = d ? Gr : Gl;
  int xoff = d ? xoffR : 0;

  const float* xp = X + (long)(b*SEQL + t0)*sx + xoff + f;
  const float* gp = G + (long)(b*SEQL + t0)*HDIM + f;
  float*       yp = Y + (long)(b*SEQL + t0)*512 + d*HDIM + f;
  long xstep = (long)stp * sx;
  long gstep = (long)stp * HDIM;
  long ystep = (long)stp * 512;

  float cx[T], cg[T], nx[T], ng[T];
  #pragma unroll
  for (int j = 0; j < T; ++j) { cx[j] = xp[xstep*j]; cg[j] = gp[gstep*j]; }

  const float C2 = -2.8853900817779268f;   // -2*log2(e)
  float h = 0.f;
  for (int c = 0; c < NC; ++c) {
    const float* xpn = xp + xstep*T;
    const float* gpn = gp + gstep*T;
    if (c + 1 < NC) {
      #pragma unroll
      for (int j = 0; j < T; ++j) { nx[j] = xpn[xstep*j]; ng[j] = gpn[gstep*j]; }
    }
    #pragma unroll
    for (int j = 0; j < T; ++j) {
      float x = cx[j], g = cg[j];
      float t1 = x * g;                 // off-chain
      float a2 = t1 * C2;               // off-chain
      float b2 = (x - t1) * x * C2;     // off-chain: x*(1-g)*x * C2
      float q  = fmaf(a2, h, b2);       // chain: q = -2*log2e * p
      q = fminf(fmaxf(q, -60.f), 60.f);
      float e2 = __builtin_amdgcn_exp2f(q);          // e^{-2p}
      float r  = __builtin_amdgcn_rcpf(1.f + e2);
      h = (1.f - e2) * r;                            // tanh(p)
      *yp = h; yp += ystep;
    }
    #pragma unroll
    for (int j = 0; j < T; ++j) { cx[j] = nx[j]; cg[j] = ng[j]; }
    xp = xpn; gp = gpn;
  }
  hout[(size_t)d*BSZ*HDIM + (size_t)b*HDIM + f] = h;
}

extern "C" void kernel_launch(void* const* d_in, const int* in_sizes, int n_in,
                              void* d_out, int out_size, void* d_ws, size_t ws_size,
                              hipStream_t stream) {
  const float* x    = (const float*)d_in[0];
  const float* W_fc = (const float*)d_in[1];
  const float* b_fc = (const float*)d_in[2];
  // d_in[3]=W1, d_in[4]=b1: mathematically dead (blending1 == identity)
  const float* W2   = (const float*)d_in[5];
  const float* b2   = (const float*)d_in[6];

  float* out  = (float*)d_out;
  float* bufA = (float*)d_ws;                      // 65536*256 f32 = 64 MiB
  float* bufB = bufA + (size_t)MTOT*HDIM;          // 64 MiB
  float* xx   = out;                               // [32][2048][512]
  float* hout = out + XXN;                         // [4][32][256]

  dim3 grid(MTOT/128, 2);

  // H0 = x @ W_fc.T + b_fc            -> bufA  [65536][256]
  gemm_bias_act<<<grid, 256, 0, stream>>>(x, 512, W_fc, 512, b_fc, bufA, 0);
  // G0 = sigmoid(H0 @ W2_0.T + b2_0)  -> bufB  (rtl gates = time-flip of same)
  gemm_bias_act<<<grid, 256, 0, stream>>>(bufA, HDIM, W2, HDIM, b2, bufB, 1);
  // layer 0 recurrence: X=H0 (both halves of xx equal), writes xx1 into d_out
  recur<<<256, 64, 0, stream>>>(bufA, HDIM, 0, bufB, bufB, xx, hout);
  // layer 1 gates (ltr from xx[:, :, :256], rtl from xx[:, :, 256:], natural t order)
  gemm_bias_act<<<grid, 256, 0, stream>>>(xx,       512, W2 + HDIM*HDIM, HDIM, b2 + HDIM, bufA, 1);
  gemm_bias_act<<<grid, 256, 0, stream>>>(xx + 256, 512, W2 + HDIM*HDIM, HDIM, b2 + HDIM, bufB, 1);
  // layer 1 recurrence, in place in d_out (each thread rewrites its own column)
  recur<<<256, 64, 0, stream>>>(xx, 512, 256, bufA, bufB, xx, hout + 2*BSZ*HDIM);
}